// Round 1
// baseline (62.414 us; speedup 1.0000x reference)
//
#include <hip/hip_runtime.h>
#include <math.h>

#define NQ      100
#define BS      8
#define NC      4
#define NPTS    30
#define NTGT    512
#define P_TOTAL (NQ*BS)   /* 800 */
#define TILE_P  8
#define TILE_T  64
#define NTHREADS 512

__global__ __launch_bounds__(NTHREADS) void matcher_kernel(
    const float* __restrict__ logits,      // [800,4]  (p = q*BS + b major)
    const float* __restrict__ pred_poly,   // [800,30,2]
    const int*   __restrict__ tgt_ids,     // [512]
    const float* __restrict__ tgt_poly,    // [512,30,2]
    float*       __restrict__ out)         // [800,512] == reshape(8,100,512) memory-identical
{
    // tgt tile transposed + padded: reads tx[j][tl] are lane-stride-1 => conflict-free
    __shared__ float tx_lds[NPTS][TILE_T + 1];
    __shared__ float ty_lds[NPTS][TILE_T + 1];
    __shared__ float px_lds[TILE_P][NPTS];
    __shared__ float py_lds[TILE_P][NPTS];
    __shared__ float prob_lds[TILE_P][NC];

    const int tid = threadIdx.x;
    const int p0  = blockIdx.x * TILE_P;
    const int t0  = blockIdx.y * TILE_T;

    // ---- stage 64 tgt polylines (64*30 float2, coalesced global reads) ----
    for (int idx = tid; idx < TILE_T * NPTS; idx += NTHREADS) {
        const int tt = idx / NPTS;
        const int j  = idx - tt * NPTS;
        const float2 v = *reinterpret_cast<const float2*>(
            tgt_poly + (size_t)(t0 + tt) * (NPTS * 2) + j * 2);
        tx_lds[j][tt] = v.x;
        ty_lds[j][tt] = v.y;
    }
    // ---- stage 8 pred polylines ----
    for (int idx = tid; idx < TILE_P * NPTS; idx += NTHREADS) {
        const int pp = idx / NPTS;
        const int i  = idx - pp * NPTS;
        const float2 v = *reinterpret_cast<const float2*>(
            pred_poly + (size_t)(p0 + pp) * (NPTS * 2) + i * 2);
        px_lds[pp][i] = v.x;
        py_lds[pp][i] = v.y;
    }
    // ---- softmax over 4 classes for the block's 8 preds ----
    if (tid < TILE_P) {
        const float* l = logits + (size_t)(p0 + tid) * NC;
        const float a0 = l[0], a1 = l[1], a2 = l[2], a3 = l[3];
        const float m  = fmaxf(fmaxf(a0, a1), fmaxf(a2, a3));
        const float e0 = expf(a0 - m), e1 = expf(a1 - m);
        const float e2 = expf(a2 - m), e3 = expf(a3 - m);
        const float inv = 1.0f / (e0 + e1 + e2 + e3);
        prob_lds[tid][0] = e0 * inv;
        prob_lds[tid][1] = e1 * inv;
        prob_lds[tid][2] = e2 * inv;
        prob_lds[tid][3] = e3 * inv;
    }
    __syncthreads();

    const int tl = tid & (TILE_T - 1);   // tgt lane within tile (wave = 64 consecutive t's)
    const int pl = tid >> 6;             // pred index within tile (wave-uniform)

    // pull my tgt polyline into registers (60 VGPRs)
    float tx[NPTS], ty[NPTS];
#pragma unroll
    for (int j = 0; j < NPTS; ++j) {
        tx[j] = tx_lds[j][tl];
        ty[j] = ty_lds[j][tl];
    }

    float m2[NPTS];
#pragma unroll
    for (int j = 0; j < NPTS; ++j) m2[j] = 1e30f;

    float sum1 = 0.0f;
    for (int i = 0; i < NPTS; ++i) {
        const float px = px_lds[pl][i];  // wave-uniform broadcast
        const float py = py_lds[pl][i];
        float dmin = 1e30f;
#pragma unroll
        for (int j = 0; j < NPTS; ++j) {
            const float d = fabsf(px - tx[j]) + fabsf(py - ty[j]);
            dmin  = fminf(dmin, d);
            m2[j] = fminf(m2[j], d);
        }
        sum1 += dmin;
    }
    float sum2 = 0.0f;
#pragma unroll
    for (int j = 0; j < NPTS; ++j) sum2 += m2[j];

    const int   t   = t0 + tl;
    const int   cls = tgt_ids[t];
    const float cc  = -prob_lds[pl][cls];
    // cost = cost_class + 0.5*(mean_i min_j + mean_j min_i)
    out[(size_t)(p0 + pl) * NTGT + t] = cc + (sum1 + sum2) * (0.5f / (float)NPTS);
}

extern "C" void kernel_launch(void* const* d_in, const int* in_sizes, int n_in,
                              void* d_out, int out_size, void* d_ws, size_t ws_size,
                              hipStream_t stream) {
    const float* logits    = (const float*)d_in[0];
    const float* pred_poly = (const float*)d_in[1];
    const int*   tids      = (const int*)d_in[2];
    const float* tgt_poly  = (const float*)d_in[3];
    float*       out       = (float*)d_out;

    dim3 grid(P_TOTAL / TILE_P, NTGT / TILE_T);  // (100, 8)
    dim3 block(NTHREADS);
    matcher_kernel<<<grid, block, 0, stream>>>(logits, pred_poly, tids, tgt_poly, out);
}

// Round 2
// 41.863 us; speedup vs baseline: 1.4909x; 1.4909x over previous
//
#include <hip/hip_runtime.h>
#include <math.h>

#define NQ      100
#define BS      8
#define NC      4
#define NPTS    30
#define NTGT    512
#define P_TOTAL (NQ*BS)   /* 800 */
#define TILE_P  8
#define TILE_T  32
#define NTHREADS 256

typedef float f32x2 __attribute__((ext_vector_type(2)));

__global__ __launch_bounds__(NTHREADS) void matcher_kernel(
    const float* __restrict__ logits,      // [800,4]
    const float* __restrict__ pred_poly,   // [800,30,2]
    const int*   __restrict__ tgt_ids,     // [512]
    const float* __restrict__ tgt_poly,    // [512,30,2]
    float*       __restrict__ out)         // [800,512]
{
    // rotated coords: s = x+y, r = x-y  =>  L1 dist = max(|ds|, |dr|)
    __shared__ f32x2 srt_t[NPTS][TILE_T + 1];  // [j][t] padded: lane-stride-1 reads
    __shared__ f32x2 srt_p[TILE_P][NPTS];
    __shared__ float prob_lds[TILE_P][NC];

    const int tid = threadIdx.x;
    const int p0  = blockIdx.x * TILE_P;
    const int t0  = blockIdx.y * TILE_T;

    // ---- stage 32 tgt polylines, rotate into (s,r) ----
    for (int idx = tid; idx < TILE_T * NPTS; idx += NTHREADS) {
        const int tt = idx / NPTS;
        const int j  = idx - tt * NPTS;
        const float2 v = *reinterpret_cast<const float2*>(
            tgt_poly + (size_t)(t0 + tt) * (NPTS * 2) + j * 2);
        srt_t[j][tt] = f32x2{v.x + v.y, v.x - v.y};
    }
    // ---- stage 8 pred polylines, rotate ----
    for (int idx = tid; idx < TILE_P * NPTS; idx += NTHREADS) {
        const int pp = idx / NPTS;
        const int i  = idx - pp * NPTS;
        const float2 v = *reinterpret_cast<const float2*>(
            pred_poly + (size_t)(p0 + pp) * (NPTS * 2) + i * 2);
        srt_p[pp][i] = f32x2{v.x + v.y, v.x - v.y};
    }
    // ---- softmax over 4 classes ----
    if (tid < TILE_P) {
        const float* l = logits + (size_t)(p0 + tid) * NC;
        const float a0 = l[0], a1 = l[1], a2 = l[2], a3 = l[3];
        const float m  = fmaxf(fmaxf(a0, a1), fmaxf(a2, a3));
        const float e0 = expf(a0 - m), e1 = expf(a1 - m);
        const float e2 = expf(a2 - m), e3 = expf(a3 - m);
        const float inv = 1.0f / (e0 + e1 + e2 + e3);
        prob_lds[tid][0] = e0 * inv;
        prob_lds[tid][1] = e1 * inv;
        prob_lds[tid][2] = e2 * inv;
        prob_lds[tid][3] = e3 * inv;
    }
    __syncthreads();

    const int tl = tid & (TILE_T - 1);   // tgt lane
    const int pl = tid >> 5;             // pred index in tile (uniform per 32-thread group)

    // my tgt polyline (rotated) in registers: 30 x float2 pairs
    f32x2 st[NPTS];
#pragma unroll
    for (int j = 0; j < NPTS; ++j) st[j] = srt_t[j][tl];

    float m2[NPTS];
#pragma unroll
    for (int j = 0; j < NPTS; ++j) m2[j] = 1e30f;

    float sum1 = 0.0f;
#pragma unroll
    for (int i = 0; i < NPTS; i += 2) {
        const f32x2 pr0 = srt_p[pl][i];      // broadcast reads
        const f32x2 pr1 = srt_p[pl][i + 1];
        float dmin0 = 1e30f, dmin1 = 1e30f;
#pragma unroll
        for (int j = 0; j < NPTS; j += 2) {
            const f32x2 w00 = pr0 - st[j];       // v_pk_add_f32 (neg)
            const f32x2 w01 = pr0 - st[j + 1];
            const f32x2 w10 = pr1 - st[j];
            const f32x2 w11 = pr1 - st[j + 1];
            const float d00 = fmaxf(fabsf(w00.x), fabsf(w00.y));  // v_max_f32 abs,abs
            const float d01 = fmaxf(fabsf(w01.x), fabsf(w01.y));
            const float d10 = fmaxf(fabsf(w10.x), fabsf(w10.y));
            const float d11 = fmaxf(fabsf(w11.x), fabsf(w11.y));
            m2[j]     = fminf(fminf(m2[j],     d00), d10);        // v_min3_f32
            m2[j + 1] = fminf(fminf(m2[j + 1], d01), d11);
            dmin0     = fminf(fminf(dmin0, d00), d01);
            dmin1     = fminf(fminf(dmin1, d10), d11);
        }
        sum1 += dmin0;
        sum1 += dmin1;
    }
    float sum2 = 0.0f;
#pragma unroll
    for (int j = 0; j < NPTS; ++j) sum2 += m2[j];

    const int   t   = t0 + tl;
    const int   cls = tgt_ids[t];
    const float cc  = -prob_lds[pl][cls];
    out[(size_t)(p0 + pl) * NTGT + t] = cc + (sum1 + sum2) * (0.5f / (float)NPTS);
}

extern "C" void kernel_launch(void* const* d_in, const int* in_sizes, int n_in,
                              void* d_out, int out_size, void* d_ws, size_t ws_size,
                              hipStream_t stream) {
    const float* logits    = (const float*)d_in[0];
    const float* pred_poly = (const float*)d_in[1];
    const int*   tids      = (const int*)d_in[2];
    const float* tgt_poly  = (const float*)d_in[3];
    float*       out       = (float*)d_out;

    dim3 grid(P_TOTAL / TILE_P, NTGT / TILE_T);  // (100, 16)
    dim3 block(NTHREADS);
    matcher_kernel<<<grid, block, 0, stream>>>(logits, pred_poly, tids, tgt_poly, out);
}